// Round 19
// baseline (56.439 us; speedup 1.0000x reference)
//
#include <hip/hip_runtime.h>
#include <hip/hip_bf16.h>
#include <math.h>

#define T_LEN   7680
#define NSEG    59
#define NBINS   45
#define CH_PB   8      // channels per block
#define NBLK    512    // 512 x 8 = 4096 channels; 2 blocks/CU (LDS 80128 x2)
#define NTHR    512    // 8 waves: 0-3 converters, 4-7 GEMM

using bf16x8 = __attribute__((ext_vector_type(8))) short;
using f32x4  = __attribute__((ext_vector_type(4))) float;

__device__ __forceinline__ unsigned f2bf(float f) {
    unsigned u = __builtin_bit_cast(unsigned, f);
    return (u + 0x7FFFu + ((u >> 16) & 1u)) >> 16;   // RNE fp32->bf16
}

// xs swizzle (R9-R18 proven): rows stride 256 B -> mix bits 8-10 into 4-6.
__device__ __forceinline__ unsigned phys(unsigned a) {
    return a ^ (((a >> 8) & 7u) << 4);
}
// mt_lds swizzle (R12-R18 proven): rows stride 512 B -> bits 9-11 into 4-6.
__device__ __forceinline__ unsigned physB(unsigned a) {
    return a ^ (((a >> 9) & 7u) << 4);
}

// Basis table mt[96][256] bf16 (detrend+window folded; R2-proven math):
//   col j=2i: w_n*cos(2pi(i+1)n/256); col j=2i+1: -w_n*sin(...);
//   col 0 adds +0.25 (exact detrend correction for k=1 real part).
__global__ void build_basis_kernel(unsigned short* __restrict__ mt) {
    int j = blockIdx.x, n = threadIdx.x;
    const float TH = 0.02454369260617026f;           // 2*pi/256
    float w = 0.5f - 0.5f * cosf((float)n * TH);     // periodic hann
    float v = 0.f;
    if (j < 90) {
        int k = (j >> 1) + 1;
        int m = (k * n) & 255;                       // exact periodic reduction
        float th = (float)m * TH;
        v = (j & 1) ? (-w * sinf(th)) : (w * cosf(th));
        if (j == 0) v += 0.25f;                      // fold detrend into k=1 re
    }
    mt[j * 256 + n] = (unsigned short)f2bf(v);
}

// Producer/consumer wave specialization: waves 0-3 convert ch c+1
// (global->reg->xs, consumed same-phase: no cross-phase reg liveness) while
// waves 4-7 GEMM ch c. ONE barrier per channel. 2 blocks/CU (80KB LDS).
// Ledger: guards OUTSIDE k0 MFMA loops (R3-R5); no breg hoist/launder
// (R7-R11); XOR applied last (R13); natural regs < 64 (R14/R15); B via
// ds_read from mt_lds (R12); junk rows via xs zero-pad + fold mask (R12).
__global__ __launch_bounds__(NTHR, 2)
void welch_main_kernel(const float* __restrict__ x,
                       const unsigned short* __restrict__ mt,
                       float* __restrict__ out) {
    __shared__ __align__(16) unsigned short mt_lds[90 * 256];  // 46080 B
    __shared__ __align__(16) unsigned short xs[2][8320];       // 33280 B
    __shared__ float psum[2][96];                              //   768 B

    const int tid  = threadIdx.x;
    const int lane = tid & 63;
    const int w    = tid >> 6;
    const int ch0  = blockIdx.x * CH_PB;

    // ---- prologue: stage mt rows 0..89 (2880 x 16B), physB-swizzled
    {
        const uint4* mt4 = reinterpret_cast<const uint4*>(mt);
        #pragma unroll
        for (int i = 0; i < 6; ++i) {
            int c = i * NTHR + tid;
            if (c < 2880) {
                uint4 v = mt4[c];
                *reinterpret_cast<uint4*>((char*)mt_lds + physB((unsigned)c * 16u)) = v;
            }
        }
    }
    // zero xs pads (samples 7680..8319, both buffers) and psum (both slots)
    if (tid < 320) {
        int b = tid / 160, o = tid - b * 160;
        unsigned a = phys(15360u + (unsigned)o * 8u);
        *reinterpret_cast<uint2*>((char*)xs[b] + a) = make_uint2(0u, 0u);
    }
    if (tid < 192) ((float*)psum)[tid] = 0.f;

    // prologue convert: ch0 -> xs[0] by ALL waves (global->reg->xs)
    {
        const float* g0 = x + (size_t)ch0 * T_LEN;
        #pragma unroll
        for (int i = 0; i < 4; ++i) {
            int c = i * NTHR + tid;
            if (c < 1920) {
                f32x4 xv = *reinterpret_cast<const f32x4*>(g0 + 4 * c);
                uint2 pk;
                pk.x = f2bf(xv[0]) | (f2bf(xv[1]) << 16);
                pk.y = f2bf(xv[2]) | (f2bf(xv[3]) << 16);
                *reinterpret_cast<uint2*>((char*)xs[0] + phys((unsigned)c * 8u)) = pk;
            }
        }
    }
    asm volatile("s_waitcnt lgkmcnt(0)" ::: "memory");
    __builtin_amdgcn_s_barrier();
    __builtin_amdgcn_sched_barrier(0);

    const int col0 = lane & 15;
    const int q    = lane >> 4;

    #pragma unroll 1
    for (int cc = 0; cc < CH_PB; ++cc) {
        const int par = cc & 1;

        if (w < 4) {
            // ---- converter team: build xs[par^1] for channel cc+1
            if (cc + 1 < CH_PB) {
                const float* gxc = x + (size_t)(ch0 + cc + 1) * T_LEN;
                char* xb = (char*)xs[par ^ 1];
                #pragma unroll 2
                for (int i = 0; i < 8; ++i) {
                    int c = i * 256 + tid;            // tid in [0,256)
                    if (c < 1920) {
                        f32x4 xv = *reinterpret_cast<const f32x4*>(gxc + 4 * c);
                        uint2 pk;
                        pk.x = f2bf(xv[0]) | (f2bf(xv[1]) << 16);
                        pk.y = f2bf(xv[2]) | (f2bf(xv[3]) << 16);
                        *reinterpret_cast<uint2*>(xb + phys((unsigned)c * 8u)) = pk;
                    }
                }
            }
        } else {
            // ---- GEMM team: channel cc from xs[par] (R2 ownership: wave
            // w4 owns pairs p=6*w4..6*w4+5, p=ct*4+rt; guards OUTSIDE k0)
            const char* xb = (const char*)xs[par];
            const int w4  = w - 4;
            const int ctA = (6 * w4) >> 2;
            const int ctB = (6 * w4 + 5) >> 2;
            int jA = ctA * 16 + col0;  if (jA > 89) jA = 89;  // col clamp
            int jB = ctB * 16 + col0;  if (jB > 89) jB = 89;  // (bins masked)
            const unsigned bbA = (unsigned)(jA * 512 + q * 16);
            const unsigned bbB = (unsigned)(jB * 512 + q * 16);
            const unsigned szA = (unsigned)((jA & 7) << 4);
            const unsigned szB = (unsigned)((jB & 7) << 4);

            float pA = 0.f, pB = 0.f;
            #pragma unroll
            for (int rt = 0; rt < 4; ++rt) {
                const unsigned abase = (unsigned)((rt * 16 + col0) * 256);
                bf16x8 a[8];
                #pragma unroll
                for (int k0 = 0; k0 < 8; ++k0)
                    a[k0] = *reinterpret_cast<const bf16x8*>(
                        xb + phys(abase + (unsigned)(k0 * 64 + q * 16)));
                f32x4 accA = (f32x4){0.f, 0.f, 0.f, 0.f};
                f32x4 accB = (f32x4){0.f, 0.f, 0.f, 0.f};
                const bool oA = (unsigned)(ctA * 4 + rt - 6 * w4) < 6u;
                const bool oB = (unsigned)(ctB * 4 + rt - 6 * w4) < 6u;
                if (oA) {
                    #pragma unroll
                    for (int k0 = 0; k0 < 8; ++k0) {
                        bf16x8 b = *reinterpret_cast<const bf16x8*>(
                            (char*)mt_lds + ((bbA + (unsigned)(k0 * 64)) ^ szA));
                        accA = __builtin_amdgcn_mfma_f32_16x16x32_bf16(
                            a[k0], b, accA, 0, 0, 0);
                    }
                }
                if (oB) {
                    #pragma unroll
                    for (int k0 = 0; k0 < 8; ++k0) {
                        bf16x8 b = *reinterpret_cast<const bf16x8*>(
                            (char*)mt_lds + ((bbB + (unsigned)(k0 * 64)) ^ szB));
                        accB = __builtin_amdgcn_mfma_f32_16x16x32_bf16(
                            a[k0], b, accB, 0, 0, 0);
                    }
                }
                // fold with junk-row mask; C/D: col=lane&15, row=rt*16+q*4+r
                const int rowbase = rt * 16 + q * 4;
                #pragma unroll
                for (int r = 0; r < 4; ++r) {
                    if (rowbase + r < NSEG) {
                        pA += accA[r] * accA[r];
                        pB += accB[r] * accB[r];
                    }
                }
            }
            pA += __shfl_xor(pA, 16);  pA += __shfl_xor(pA, 32);
            pB += __shfl_xor(pB, 16);  pB += __shfl_xor(pB, 32);
            if (lane < 16) {
                atomicAdd(&psum[par][ctA * 16 + col0], pA);
                atomicAdd(&psum[par][ctB * 16 + col0], pB);
            }

            // ---- wave 4: output ch cc-1 from slot par^1, then zero it
            // (slot par^1 is ch cc+1's slot; barrier below orders the zeroing
            // before iteration cc+1's atomics)
            if (w4 == 0 && cc > 0) {
                const float CNORM = 2.0f / (24576.0f * 59.0f);
                if (lane < NBINS) {
                    float psd = (psum[par ^ 1][2 * lane] + psum[par ^ 1][2 * lane + 1]) * CNORM;
                    out[(size_t)(ch0 + cc - 1) * NBINS + lane] = log1pf(psd);
                }
                asm volatile("s_waitcnt lgkmcnt(0)" ::: "memory");
                psum[par ^ 1][lane] = 0.f;
                if (lane < 32) psum[par ^ 1][64 + lane] = 0.f;
            }
        }

        asm volatile("s_waitcnt lgkmcnt(0)" ::: "memory");
        __builtin_amdgcn_s_barrier();
        __builtin_amdgcn_sched_barrier(0);
    }

    // ---- epilogue: last channel's output (atomics ordered by final barrier)
    if (w == 4) {
        const int qo = (CH_PB - 1) & 1;
        const float CNORM = 2.0f / (24576.0f * 59.0f);
        if (lane < NBINS) {
            float psd = (psum[qo][2 * lane] + psum[qo][2 * lane + 1]) * CNORM;
            out[(size_t)(ch0 + CH_PB - 1) * NBINS + lane] = log1pf(psd);
        }
    }
}

extern "C" void kernel_launch(void* const* d_in, const int* in_sizes, int n_in,
                              void* d_out, int out_size, void* d_ws, size_t ws_size,
                              hipStream_t stream) {
    const float* x = (const float*)d_in[0];
    float* out = (float*)d_out;
    unsigned short* mt = (unsigned short*)d_ws;   // 96*256*2 = 49152 B

    build_basis_kernel<<<96, 256, 0, stream>>>(mt);
    welch_main_kernel<<<NBLK, NTHR, 0, stream>>>(x, mt, out);
}

// Round 20
// 42.038 us; speedup vs baseline: 1.3426x; 1.3426x over previous
//
#include <hip/hip_runtime.h>
#include <hip/hip_bf16.h>
#include <math.h>

#define T_LEN   7680
#define NSEG    59
#define NBINS   45
#define CH_PB   8      // channels per block
#define NBLK    512    // 512 x 8 = 4096 channels; 2 blocks/CU (LDS 77568 x2)
#define NTHR    512    // 8 waves

using bf16x8 = __attribute__((ext_vector_type(8))) short;
using f32x4  = __attribute__((ext_vector_type(4))) float;

__device__ __forceinline__ unsigned f2bf(float f) {
    unsigned u = __builtin_bit_cast(unsigned, f);
    return (u + 0x7FFFu + ((u >> 16) & 1u)) >> 16;   // RNE fp32->bf16
}

// xs swizzle (R9-R19 proven): rows stride 256 B -> mix bits 8-10 into 4-6.
__device__ __forceinline__ unsigned phys(unsigned a) {
    return a ^ (((a >> 8) & 7u) << 4);
}
// mt_lds swizzle (R12-R19 proven): rows stride 512 B -> bits 9-11 into 4-6.
__device__ __forceinline__ unsigned physB(unsigned a) {
    return a ^ (((a >> 9) & 7u) << 4);
}

// Basis table mt[96][256] bf16 (detrend+window folded; R2-proven math):
//   col j=2i: w_n*cos(2pi(i+1)n/256); col j=2i+1: -w_n*sin(...);
//   col 0 adds +0.25 (exact detrend correction for k=1 real part).
__global__ void build_basis_kernel(unsigned short* __restrict__ mt) {
    int j = blockIdx.x, n = threadIdx.x;
    const float TH = 0.02454369260617026f;           // 2*pi/256
    float w = 0.5f - 0.5f * cosf((float)n * TH);     // periodic hann
    float v = 0.f;
    if (j < 90) {
        int k = (j >> 1) + 1;
        int m = (k * n) & 255;                       // exact periodic reduction
        float th = (float)m * TH;
        v = (j & 1) ? (-w * sinf(th)) : (w * cosf(th));
        if (j == 0) v += 0.25f;                      // fold detrend into k=1 re
    }
    mt[j * 256 + n] = (unsigned short)f2bf(v);
}

// R12 fortress + in-wave pipeline: issue ch c+1 loads -> GEMM ch c (hides the
// ~900cy HBM latency under ~2000cy of ds_read+MFMA) -> convert -> ONE barrier.
// xs double-buffered (15360B each; junk rows clamped + fold-masked, no pad).
// Registers: loads 16 + a[8] 32 + acc 4 + b 4 + misc ~15 = 71 < 84 tier
// (R7's spill was demand ~140). LDS 77568 x2 = 155136 <= 163840 with margin
// (R19 died on a 3KB LDS cliff -> 1 block/CU).
// Ledger: no MFMA guards (R3-R5); no breg hoist/launder (R7-R11); XOR last
// (R13); junk rows clamp+mask (R15); B via ds_read (R12); raw s_barrier +
// lgkmcnt (R18-proven) so held vmem loads stay in flight across the barrier.
__global__ __launch_bounds__(NTHR, 2)
void welch_main_kernel(const float* __restrict__ x,
                       const unsigned short* __restrict__ mt,
                       float* __restrict__ out) {
    __shared__ __align__(16) unsigned short mt_lds[90 * 256];  // 46080 B
    __shared__ __align__(16) unsigned short xs[2][7680];       // 30720 B
    __shared__ float psum[2][96];                              //   768 B

    const int tid  = threadIdx.x;
    const int lane = tid & 63;
    const int w    = tid >> 6;
    const int ch0  = blockIdx.x * CH_PB;

    // ---- prologue: stage mt rows 0..89 (2880 x 16B), physB-swizzled
    {
        const uint4* mt4 = reinterpret_cast<const uint4*>(mt);
        #pragma unroll
        for (int i = 0; i < 6; ++i) {
            int c = i * NTHR + tid;
            if (c < 2880) {
                uint4 v = mt4[c];
                *reinterpret_cast<uint4*>((char*)mt_lds + physB((unsigned)c * 16u)) = v;
            }
        }
    }
    if (tid < 192) ((float*)psum)[tid] = 0.f;
    // prologue convert: ch0 -> xs[0] by all waves
    {
        const float* g0 = x + (size_t)ch0 * T_LEN;
        #pragma unroll
        for (int i = 0; i < 4; ++i) {
            int c = i * NTHR + tid;
            if (c < 1920) {
                f32x4 xv = *reinterpret_cast<const f32x4*>(g0 + 4 * c);
                uint2 pk;
                pk.x = f2bf(xv[0]) | (f2bf(xv[1]) << 16);
                pk.y = f2bf(xv[2]) | (f2bf(xv[3]) << 16);
                *reinterpret_cast<uint2*>((char*)xs[0] + phys((unsigned)c * 8u)) = pk;
            }
        }
    }
    asm volatile("s_waitcnt lgkmcnt(0)" ::: "memory");
    __builtin_amdgcn_s_barrier();
    __builtin_amdgcn_sched_barrier(0);

    const int col0 = lane & 15;
    const int q    = lane >> 4;
    const int rt   = w & 3;               // R12 ownership: same rt, 3 cts
    const int ctb  = w >> 2;
    const unsigned kq16 = (unsigned)(q * 16);
    const int rowbase   = rt * 16 + q * 4;
    const int row       = rt * 16 + col0;
    const int row_eff   = row > 58 ? 58 : row;          // clamp junk rows
    const unsigned abase = (unsigned)(row_eff * 256);

    #pragma unroll 1
    for (int cc = 0; cc < CH_PB; ++cc) {
        const int par = cc & 1;
        const bool more = (cc + 1 < CH_PB);

        // ---- issue next channel's loads FIRST (latency hides under GEMM)
        f32x4 xv0, xv1, xv2, xv3;
        if (more) {
            const float* gn = x + (size_t)(ch0 + cc + 1) * T_LEN;
            xv0 = *reinterpret_cast<const f32x4*>(gn + 4 * tid);
            xv1 = *reinterpret_cast<const f32x4*>(gn + 4 * (tid + 512));
            xv2 = *reinterpret_cast<const f32x4*>(gn + 4 * (tid + 1024));
            if (tid + 1536 < 1920)
                xv3 = *reinterpret_cast<const f32x4*>(gn + 4 * (tid + 1536));
        }

        // ---- GEMM ch cc from xs[par] (R12-verbatim: a[8] once, 3 chains)
        {
            const char* xb = (const char*)xs[par];
            bf16x8 a[8];
            #pragma unroll
            for (int k0 = 0; k0 < 8; ++k0)
                a[k0] = *reinterpret_cast<const bf16x8*>(
                    xb + phys(abase + (unsigned)(k0 * 64) + kq16));
            #pragma unroll
            for (int m = 0; m < 3; ++m) {
                const int ct = ctb + 2 * m;
                int j = ct * 16 + col0;
                if (j > 89) j = 89;        // dummy cols -> col89 (bins masked)
                const unsigned bb = (unsigned)(j * 512) + kq16;
                const unsigned sz = (unsigned)((j & 7) << 4);
                f32x4 acc = (f32x4){0.f, 0.f, 0.f, 0.f};
                #pragma unroll
                for (int k0 = 0; k0 < 8; ++k0) {
                    bf16x8 b = *reinterpret_cast<const bf16x8*>(
                        (char*)mt_lds + ((bb + (unsigned)(k0 * 64)) ^ sz));
                    acc = __builtin_amdgcn_mfma_f32_16x16x32_bf16(a[k0], b, acc, 0, 0, 0);
                }
                float p = 0.f;
                #pragma unroll
                for (int r = 0; r < 4; ++r)
                    if (rowbase + r < NSEG) p += acc[r] * acc[r];
                p += __shfl_xor(p, 16);
                p += __shfl_xor(p, 32);
                if (lane < 16) atomicAdd(&psum[par][ct * 16 + col0], p);
            }
        }

        // ---- convert held regs -> xs[par^1] (next channel's data)
        if (more) {
            char* xb = (char*)xs[par ^ 1];
            uint2 pk;
            pk.x = f2bf(xv0[0]) | (f2bf(xv0[1]) << 16);
            pk.y = f2bf(xv0[2]) | (f2bf(xv0[3]) << 16);
            *reinterpret_cast<uint2*>(xb + phys((unsigned)tid * 8u)) = pk;
            pk.x = f2bf(xv1[0]) | (f2bf(xv1[1]) << 16);
            pk.y = f2bf(xv1[2]) | (f2bf(xv1[3]) << 16);
            *reinterpret_cast<uint2*>(xb + phys((unsigned)(tid + 512) * 8u)) = pk;
            pk.x = f2bf(xv2[0]) | (f2bf(xv2[1]) << 16);
            pk.y = f2bf(xv2[2]) | (f2bf(xv2[3]) << 16);
            *reinterpret_cast<uint2*>(xb + phys((unsigned)(tid + 1024) * 8u)) = pk;
            if (tid + 1536 < 1920) {
                pk.x = f2bf(xv3[0]) | (f2bf(xv3[1]) << 16);
                pk.y = f2bf(xv3[2]) | (f2bf(xv3[3]) << 16);
                *reinterpret_cast<uint2*>(xb + phys((unsigned)(tid + 1536) * 8u)) = pk;
            }
        }

        // ---- single barrier: atomics + xs[par^1] writes all visible
        asm volatile("s_waitcnt lgkmcnt(0)" ::: "memory");
        __builtin_amdgcn_s_barrier();
        __builtin_amdgcn_sched_barrier(0);

        // ---- output ch cc + zero psum[par] (next atomics to this slot come
        // only after the NEXT barrier -> same-epoch zeroing is safe)
        if (w == 0) {
            const float CNORM = 2.0f / (24576.0f * 59.0f);  // fs*sum(w^2)*nseg
            if (lane < NBINS) {
                float psd = (psum[par][2 * lane] + psum[par][2 * lane + 1]) * CNORM;
                out[(size_t)(ch0 + cc) * NBINS + lane] = log1pf(psd);
            }
            asm volatile("s_waitcnt lgkmcnt(0)" ::: "memory");
            psum[par][lane] = 0.f;
            if (lane < 32) psum[par][64 + lane] = 0.f;
        }
    }
}

extern "C" void kernel_launch(void* const* d_in, const int* in_sizes, int n_in,
                              void* d_out, int out_size, void* d_ws, size_t ws_size,
                              hipStream_t stream) {
    const float* x = (const float*)d_in[0];
    float* out = (float*)d_out;
    unsigned short* mt = (unsigned short*)d_ws;   // 96*256*2 = 49152 B

    build_basis_kernel<<<96, 256, 0, stream>>>(mt);
    welch_main_kernel<<<NBLK, NTHR, 0, stream>>>(x, mt, out);
}